// Round 4
// baseline (60.361 us; speedup 1.0000x reference)
//
#include <hip/hip_runtime.h>

#define NCTX 2048
#define NH   8
#define WD   32
#define NTOK 512

static constexpr float SCALE = 0.04419417382415922f; // 1/sqrt(512)

typedef float f32x16 __attribute__((ext_vector_type(16)));

// wave = 64 rows (lane = row) x JPW j's; q/v rows are wave-uniform -> s_load to SGPRs.
// block = 1024 thr = 16 waves. PARTIAL: block covers half the j range, writes
// (acc,l) partials to ws; combine kernel sums the two halves and normalizes.
template<int JPW, bool PARTIAL>
__global__ __launch_bounds__(1024, 4) void l1attn_main(
    const float* __restrict__ q, const float* __restrict__ k,
    const float* __restrict__ v, const int* __restrict__ indx,
    float* __restrict__ dst /* PARTIAL ? ws : out */) {
  __shared__ int   indxS[NTOK];
  __shared__ float accS[64 * 33];   // [row][w] stride 33 -> (lane+w)%32 banks, 2-way free
  __shared__ float lS[64];

  const int tid = threadIdx.x;
  if (tid < NTOK) indxS[tid] = indx[tid];
  for (int i = tid; i < 64 * 33; i += 1024) accS[i] = 0.f;
  if (tid < 64) lS[tid] = 0.f;
  __syncthreads();

  const int wave = __builtin_amdgcn_readfirstlane(tid >> 6); // 0..15
  const int lane = tid & 63;

  int pr, jbase;
  if (PARTIAL) { pr = blockIdx.x >> 1; jbase = ((blockIdx.x & 1) * 16 + wave) * 16; }
  else         { pr = blockIdx.x;      jbase = wave * 32; }
  const int plane = pr >> 3;    // b*8 + h
  const int rg    = pr & 7;
  const int b     = plane >> 3;
  const int h     = plane & 7;

  const float* qb = q + ((size_t)b * NCTX * NH + h) * WD;
  const float* vb = v + ((size_t)b * NCTX * NH + h) * WD;
  const float* kb = k + ((size_t)b * NCTX * NH + h) * WD;

  // per-lane K row (row s keys on k per the einsum relabeling)
  float kg[32];
  {
    const int s = rg * 64 + lane;
    const float4* kr = (const float4*)(kb + (size_t)indxS[s] * (NH * WD));
#pragma unroll
    for (int i = 0; i < 8; ++i) {
      float4 t = kr[i];
      kg[4*i+0] = t.x; kg[4*i+1] = t.y; kg[4*i+2] = t.z; kg[4*i+3] = t.w;
    }
  }

  float acc[32];
#pragma unroll
  for (int i = 0; i < 32; ++i) acc[i] = 0.f;
  float l = 0.f;

  int tok = __builtin_amdgcn_readfirstlane(indxS[jbase]);
  for (int jj = 0; jj < JPW; ++jj) {
    const int tokn =
        __builtin_amdgcn_readfirstlane(indxS[jbase + ((jj + 1) & (JPW - 1))]);
    const float* qp = qb + (size_t)tok * (NH * WD);   // wave-uniform
    const float* vp = vb + (size_t)tok * (NH * WD);

    f32x16 q0, q1, v0, v1;
    asm volatile(
        "s_load_dwordx16 %0, %4, 0x0\n\t"
        "s_load_dwordx16 %1, %4, 0x40\n\t"
        "s_load_dwordx16 %2, %5, 0x0\n\t"
        "s_load_dwordx16 %3, %5, 0x40\n\t"
        "s_waitcnt lgkmcnt(0)"
        : "=&s"(q0), "=&s"(q1), "=&s"(v0), "=&s"(v1)
        : "s"(qp), "s"(vp));

    // L1 distance over the full 32-w row, 4 independent chains
    float d0, d1, d2, d3;
    d0 = fabsf(q0[0] - kg[0]);
    d1 = fabsf(q0[1] - kg[1]);
    d2 = fabsf(q0[2] - kg[2]);
    d3 = fabsf(q0[3] - kg[3]);
#pragma unroll
    for (int i = 1; i < 4; ++i) {
      d0 += fabsf(q0[4*i+0] - kg[4*i+0]);
      d1 += fabsf(q0[4*i+1] - kg[4*i+1]);
      d2 += fabsf(q0[4*i+2] - kg[4*i+2]);
      d3 += fabsf(q0[4*i+3] - kg[4*i+3]);
    }
#pragma unroll
    for (int i = 0; i < 4; ++i) {
      d0 += fabsf(q1[4*i+0] - kg[16+4*i+0]);
      d1 += fabsf(q1[4*i+1] - kg[16+4*i+1]);
      d2 += fabsf(q1[4*i+2] - kg[16+4*i+2]);
      d3 += fabsf(q1[4*i+3] - kg[16+4*i+3]);
    }
    const float d = (d0 + d1) + (d2 + d3);
    const float p = __expf(-SCALE * d);   // d in [0,~350]: no max-shift needed
    l += p;
#pragma unroll
    for (int i = 0; i < 16; ++i) {
      acc[i]      = fmaf(p, v0[i], acc[i]);
      acc[16 + i] = fmaf(p, v1[i], acc[16 + i]);
    }
    tok = tokn;
  }

  // combine the 16 j-chunk partials in LDS
#pragma unroll
  for (int w = 0; w < 32; ++w) atomicAdd(&accS[lane * 33 + w], acc[w]);
  atomicAdd(&lS[lane], l);
  __syncthreads();

  if (PARTIAL) {
    float* wsB = dst + (size_t)blockIdx.x * 2176;   // 64*33 + 64
    for (int i = tid; i < 64 * 33; i += 1024) wsB[i] = accS[i];
    if (tid < 64) wsB[64 * 33 + tid] = lS[tid];
  } else {
#pragma unroll
    for (int idx = tid; idx < 2048; idx += 1024) {
      const int r = idx >> 5, w = idx & 31;
      dst[(((size_t)b * NTOK + rg * 64 + r) * NH + h) * WD + w] =
          accS[r * 33 + w] / lS[r];
    }
  }
}

__global__ __launch_bounds__(1024) void l1attn_combine(
    const float* __restrict__ ws, float* __restrict__ out) {
  const int gid = blockIdx.x * 1024 + threadIdx.x;  // [0, 262144)
  const int w  = gid & 31;
  const int r  = (gid >> 5) & 63;
  const int pr = gid >> 11;                         // [0, 128)
  const int b  = pr >> 6, h = (pr >> 3) & 7, rg = pr & 7;
  const float* pa = ws + (size_t)(2 * pr)     * 2176;
  const float* pb = ws + (size_t)(2 * pr + 1) * 2176;
  const float acc = pa[r * 33 + w] + pb[r * 33 + w];
  const float lsum = pa[2112 + r] + pb[2112 + r];
  out[(((size_t)b * NTOK + rg * 64 + r) * NH + h) * WD + w] = acc / lsum;
}

extern "C" void kernel_launch(void* const* d_in, const int* in_sizes, int n_in,
                              void* d_out, int out_size, void* d_ws, size_t ws_size,
                              hipStream_t stream) {
  const float* q    = (const float*)d_in[0];
  const float* k    = (const float*)d_in[1];
  const float* v    = (const float*)d_in[2];
  const int*   indx = (const int*)d_in[3];
  float*       out  = (float*)d_out;

  const size_t need = (size_t)256 * 2176 * sizeof(float);  // ~2.2 MB
  if (ws_size >= need) {
    hipLaunchKernelGGL((l1attn_main<16, true>), dim3(256), dim3(1024), 0, stream,
                       q, k, v, indx, (float*)d_ws);
    hipLaunchKernelGGL(l1attn_combine, dim3(256), dim3(1024), 0, stream,
                       (const float*)d_ws, out);
  } else {
    hipLaunchKernelGGL((l1attn_main<32, false>), dim3(128), dim3(1024), 0, stream,
                       q, k, v, indx, out);
  }
}